// Round 10
// baseline (260.714 us; speedup 1.0000x reference)
//
#include <hip/hip_runtime.h>

// Problem constants (B=8, L=1024, D=1024, H=16, DH=64)
#define B_  8
#define L_  1024
#define D_  1024
#define H_  16
#define DH_ 64

typedef unsigned short u16;
typedef __attribute__((ext_vector_type(8))) short short8;      // 8 x u16 bag (bf16)
typedef __attribute__((ext_vector_type(8))) _Float16 half8;    // 8 x f16
typedef __attribute__((ext_vector_type(4))) float floatx4;     // 16x16 C/D frag
typedef __attribute__((ext_vector_type(16))) float floatx16;   // 32x32 C/D frag

// fp32 -> bf16 round-to-nearest-even
static __device__ __forceinline__ u16 f2bf(float f) {
  union { float f; unsigned u; } cv; cv.f = f;
  unsigned u = cv.u;
  return (u16)((u + 0x7fffu + ((u >> 16) & 1u)) >> 16);
}
// fp32 -> f16 (RNE)
static __device__ __forceinline__ u16 f2h(float f) {
  union { _Float16 h; u16 u; } cv; cv.h = (_Float16)f; return cv.u;
}
// pack two fp32 -> two bf16 via v_perm; low u16 = a, high u16 = b
static __device__ __forceinline__ unsigned pack_bf2(float a, float b) {
  union { float f; unsigned u; } ua, ub; ua.f = a; ub.f = b;
  return __builtin_amdgcn_perm(ub.u + 0x8000u, ua.u + 0x8000u, 0x07060302u);
}

#if __has_builtin(__builtin_amdgcn_exp2f)
#define EXP2(x) __builtin_amdgcn_exp2f(x)
#else
#define EXP2(x) __expf((x) * 0.6931471805599453f)
#endif

// ---------------------------------------------------------------- fused casts + bias permute
// blocks [0,12288): cast x/Wq/Wk/Wv/Wo fp32 -> f16
// blocks [12288,16384): permuted bias^T table, PRE-MULTIPLIED by log2(e)
__global__ void cast_all(const float* __restrict__ x,  const float* __restrict__ wq,
                         const float* __restrict__ wk, const float* __restrict__ wv,
                         const float* __restrict__ wo, const float* __restrict__ mask,
                         u16* __restrict__ xf,  u16* __restrict__ wqf,
                         u16* __restrict__ wkf, u16* __restrict__ wvf,
                         u16* __restrict__ wof, float* __restrict__ biasP) {
  int blk = blockIdx.x;
  if (blk >= 12288) {
    int i = (blk - 12288) * 256 + threadIdx.x;
    int e = i & 3, lane = (i >> 2) & 63, rr = (i >> 8) & 3, t = (i >> 10) & 1;
    int c = (i >> 11) & 15, w = (i >> 15) & 3, qt = i >> 17;
    int kk  = e + 8 * rr + 4 * (lane >> 5);
    int row = qt * 128 + w * 32 + (lane & 31);
    int key = c * 64 + t * 32 + kk;
    // log2e * ((mask-1)*1.25e8 - 24)
    biasP[i] = (mask[(size_t)row * L_ + key] - 1.0f) * 1.8033688e8f - 34.624681f;
    return;
  }
  const float* src; u16* dst; int off;
  if (blk < 8192)       { src = x;  dst = xf;  off = blk; }
  else if (blk < 9216)  { src = wq; dst = wqf; off = blk - 8192; }
  else if (blk < 10240) { src = wk; dst = wkf; off = blk - 9216; }
  else if (blk < 11264) { src = wv; dst = wvf; off = blk - 10240; }
  else                  { src = wo; dst = wof; off = blk - 11264; }
  int i = off * 1024 + threadIdx.x * 4;
  float4 f = *(const float4*)(src + i);
  ushort4 r;
  r.x = f2h(f.x); r.y = f2h(f.y); r.z = f2h(f.z); r.w = f2h(f.w);
  *(ushort4*)(dst + i) = r;
}

// ---------------------------------------------------------------- LDS staging helper
typedef __attribute__((address_space(3))) void  lds_void;
typedef const __attribute__((address_space(1))) void g_void;
static __device__ __forceinline__ void load_lds16(const void* g, void* l) {
  __builtin_amdgcn_global_load_lds((g_void*)g, (lds_void*)l, 16, 0, 0);
}

// ---------------------------------------------------------------- fused QKV GEMM (BT), f16 inputs
// grid (24, 64): n-blocks 0-7 -> q (scale 1/8*log2e, f16), 8-15 -> k (f16),
// 16-23 -> v (bf16, written DIRECTLY in transposed+key-permuted vt layout
// from registers -- no LDS roundtrip. Derivation: a thread's 16 acc values
// per ni form two 8-contiguous-pos runs: mi-pairs (0,2) at pos 8kg+2r+{0,1},
// (1,3) at pos 32+8kg+2r+{0,1}, since pos = 2*(l&31)+(l>>5).)
// K-loop: LDS double-buffered BK=32 tiles, counted vmcnt(4), chunk-XOR swizzle
// (PMC-verified 0 bank conflicts). 682 TF.
__global__ __launch_bounds__(256) void gemm_qkv(const u16* __restrict__ A,
                                                const u16* __restrict__ wq,
                                                const u16* __restrict__ wk,
                                                const u16* __restrict__ wv,
                                                u16* __restrict__ qf,
                                                u16* __restrict__ kf,
                                                u16* __restrict__ vt) {
  const int K = D_, N = D_;
  int nb = blockIdx.x;
  const u16* Bw; u16* Cp; float scale; int obf;
  if (nb < 8)       { Bw = wq; Cp = qf; scale = 0.18033688f; obf = 0; }  // 0.125*log2e
  else if (nb < 16) { Bw = wk; Cp = kf; scale = 1.0f;        obf = 0; }
  else              { Bw = wv; Cp = vt; scale = 1.0f;        obf = 1; }
  const int n0 = (nb & 7) * 128;

  __shared__ u16 lA[2 * 128 * 32];   // double-buffered A tile
  __shared__ u16 lB[2 * 128 * 32];   // double-buffered B tile
  const int tid  = threadIdx.x;
  const int w    = tid >> 6;
  const int lane = tid & 63;
  const int m    = lane & 15;
  const int kg   = lane >> 4;
  const int m0   = blockIdx.y * 128;
  const int wm   = (w >> 1) * 64;
  const int wn   = (w & 1) * 64;
  const int rowS = tid >> 2;
  const int part = tid & 3;
  // swizzle: stored chunk c' holds global chunk c' ^ ((row>>1)&3)
  const int csrc8 = ((part ^ ((rowS >> 1) & 3))) * 8;   // staging source column
  const int kgs   = (kg ^ ((m >> 1) & 3)) * 8;          // fragment read column

  floatx4 acc[4][4];
#pragma unroll
  for (int i = 0; i < 4; ++i)
#pragma unroll
    for (int j = 0; j < 4; ++j)
#pragma unroll
      for (int r = 0; r < 4; ++r) acc[i][j][r] = 0.0f;

  auto STAGE = [&](int k0, int bufsel) {
#pragma unroll
    for (int rnd = 0; rnd < 2; ++rnd) {
      const u16* ga = A  + (size_t)(m0 + rnd * 64 + rowS) * K + k0 + csrc8;
      const u16* gb = Bw + (size_t)(n0 + rnd * 64 + rowS) * K + k0 + csrc8;
      load_lds16(ga, lA + bufsel * 4096 + rnd * 2048 + w * 512);
      load_lds16(gb, lB + bufsel * 4096 + rnd * 2048 + w * 512);
    }
  };

  STAGE(0, 0);
  STAGE(32, 1);

  for (int k0 = 0; k0 < K; k0 += 32) {
    const int buf = (k0 >> 5) & 1;
    if (k0 + 32 < K) { asm volatile("s_waitcnt vmcnt(4)" ::: "memory"); }
    else             { asm volatile("s_waitcnt vmcnt(0)" ::: "memory"); }
    __builtin_amdgcn_s_barrier();
    __builtin_amdgcn_sched_barrier(0);

    const u16* pA = lA + buf * 4096;
    const u16* pB = lB + buf * 4096;
    half8 af[4], bf[4];
#pragma unroll
    for (int i = 0; i < 4; ++i) af[i] = *(const half8*)&pA[(wm + i * 16 + m) * 32 + kgs];
#pragma unroll
    for (int i = 0; i < 4; ++i) bf[i] = *(const half8*)&pB[(wn + i * 16 + m) * 32 + kgs];
#pragma unroll
    for (int mi = 0; mi < 4; ++mi)
#pragma unroll
      for (int ni = 0; ni < 4; ++ni)
        acc[mi][ni] = __builtin_amdgcn_mfma_f32_16x16x32_f16(af[mi], bf[ni], acc[mi][ni], 0, 0, 0);

    __builtin_amdgcn_sched_barrier(0);
    __builtin_amdgcn_s_barrier();
    if (k0 + 64 < K) STAGE(k0 + 64, buf);
  }

  if (!obf) {
    // q/k: normal f16 store
#pragma unroll
    for (int mi = 0; mi < 4; ++mi)
#pragma unroll
      for (int ni = 0; ni < 4; ++ni)
#pragma unroll
        for (int r = 0; r < 4; ++r) {
          int row = m0 + wm + mi * 16 + kg * 4 + r;
          int col = n0 + wn + ni * 16 + m;
          Cp[(size_t)row * N + col] = f2h(acc[mi][ni][r] * scale);
        }
  } else {
    // V: direct transposed+permuted bf16 stores from registers.
    // This block's V-output tile: rows m0..m0+127 (keys), cols n0..n0+127 (e).
    // h = (nb&7)*2 + (wn>>6), dh = ni*16+m, 64-chunk base = (m0&1023)+wm.
    const int b   = m0 >> 10;
    const int l0v = (m0 & 1023) + wm;
    const int h   = (nb & 7) * 2 + (wn >> 6);
#pragma unroll
    for (int ni = 0; ni < 4; ++ni) {
      union { unsigned u[4]; short8 s8; } runA, runB;
#pragma unroll
      for (int r = 0; r < 4; ++r) {
        runA.u[r] = pack_bf2(acc[0][ni][r], acc[2][ni][r]);  // pos 8kg+2r, +1
        runB.u[r] = pack_bf2(acc[1][ni][r], acc[3][ni][r]);  // pos 32+8kg+2r, +1
      }
      u16* base = vt + ((size_t)((b * H_ + h) * DH_ + ni * 16 + m)) * L_ + l0v;
      *(short8*)(base + 8 * kg)      = runA.s8;
      *(short8*)(base + 32 + 8 * kg) = runB.s8;
    }
  }
}

// ---------------------------------------------------------------- final GEMM (BT), f16 in, fp32 out
__global__ __launch_bounds__(256) void gemm_fin(const u16* __restrict__ A,
                                                const u16* __restrict__ Bw,
                                                float* __restrict__ Cp,
                                                int M, int N, int K) {
  __shared__ u16 lA[2 * 128 * 32];
  __shared__ u16 lB[2 * 128 * 32];
  const int tid  = threadIdx.x;
  const int w    = tid >> 6;
  const int lane = tid & 63;
  const int m    = lane & 15;
  const int kg   = lane >> 4;
  const int m0   = blockIdx.y * 128;
  const int n0   = blockIdx.x * 128;
  const int wm   = (w >> 1) * 64;
  const int wn   = (w & 1) * 64;
  const int rowS = tid >> 2;
  const int part = tid & 3;
  const int csrc8 = ((part ^ ((rowS >> 1) & 3))) * 8;
  const int kgs   = (kg ^ ((m >> 1) & 3)) * 8;

  floatx4 acc[4][4];
#pragma unroll
  for (int i = 0; i < 4; ++i)
#pragma unroll
    for (int j = 0; j < 4; ++j)
#pragma unroll
      for (int r = 0; r < 4; ++r) acc[i][j][r] = 0.0f;

  auto STAGE = [&](int k0, int bufsel) {
#pragma unroll
    for (int rnd = 0; rnd < 2; ++rnd) {
      const u16* ga = A  + (size_t)(m0 + rnd * 64 + rowS) * K + k0 + csrc8;
      const u16* gb = Bw + (size_t)(n0 + rnd * 64 + rowS) * K + k0 + csrc8;
      load_lds16(ga, lA + bufsel * 4096 + rnd * 2048 + w * 512);
      load_lds16(gb, lB + bufsel * 4096 + rnd * 2048 + w * 512);
    }
  };

  STAGE(0, 0);
  STAGE(32, 1);

  for (int k0 = 0; k0 < K; k0 += 32) {
    const int buf = (k0 >> 5) & 1;
    if (k0 + 32 < K) { asm volatile("s_waitcnt vmcnt(4)" ::: "memory"); }
    else             { asm volatile("s_waitcnt vmcnt(0)" ::: "memory"); }
    __builtin_amdgcn_s_barrier();
    __builtin_amdgcn_sched_barrier(0);

    const u16* pA = lA + buf * 4096;
    const u16* pB = lB + buf * 4096;
    half8 af[4], bf[4];
#pragma unroll
    for (int i = 0; i < 4; ++i) af[i] = *(const half8*)&pA[(wm + i * 16 + m) * 32 + kgs];
#pragma unroll
    for (int i = 0; i < 4; ++i) bf[i] = *(const half8*)&pB[(wn + i * 16 + m) * 32 + kgs];
#pragma unroll
    for (int mi = 0; mi < 4; ++mi)
#pragma unroll
      for (int ni = 0; ni < 4; ++ni)
        acc[mi][ni] = __builtin_amdgcn_mfma_f32_16x16x32_f16(af[mi], bf[ni], acc[mi][ni], 0, 0, 0);

    __builtin_amdgcn_sched_barrier(0);
    __builtin_amdgcn_s_barrier();
    if (k0 + 64 < K) STAGE(k0 + 64, buf);
  }

#pragma unroll
  for (int mi = 0; mi < 4; ++mi)
#pragma unroll
    for (int ni = 0; ni < 4; ++ni)
#pragma unroll
      for (int r = 0; r < 4; ++r) {
        int row = m0 + wm + mi * 16 + kg * 4 + r;
        int col = n0 + wn + ni * 16 + m;
        Cp[(size_t)row * N + col] = acc[mi][ni][r];
      }
}

// ---------------------------------------------------------------- fused flash attention, 32x32 MFMA
// grid (bh=128, qt=8). 4 waves x 32 q-rows = 128 rows/block. 64-key chunks.
// Round-4 proven version (register diet, <=128 regs, 4 waves/SIMD).
__global__ __launch_bounds__(256, 4) void attn_kernel(const u16* __restrict__ q,
                                                      const u16* __restrict__ k,
                                                      const u16* __restrict__ vt,
                                                      const float* __restrict__ biasP,
                                                      u16* __restrict__ o) {
  __shared__ u16 lK[64][72];       // f16, [key][dh]
  __shared__ u16 lVt[64][72];      // bf16, [dh][pos] (permuted keys)
  __shared__ float lRS[4][32];     // per-wave rowsum broadcast

  const int bh = blockIdx.x, qt = blockIdx.y;
  const int b = bh >> 4, h = bh & 15;
  const int tid = threadIdx.x;
  const int w = tid >> 6, lane = tid & 63;
  const int c32 = lane & 31, hi = lane >> 5;
  const int qr0 = qt * 128 + w * 32;

  const int srow  = tid >> 3;      // 0..31 (stages 2 rows via it)
  const int skoff = (tid & 7) * 8;

  // Q B-frags: lane holds Q[q=qr0+c32][dh-slice ks*16+hi*8]
  const size_t qbase = ((size_t)((b * L_ + qr0 + c32) * H_ + h)) * DH_;
  half8 aq[4];
#pragma unroll
  for (int ks = 0; ks < 4; ++ks)
    aq[ks] = *(const half8*)(q + qbase + ks * 16 + hi * 8);

  floatx16 acc0, acc1;
#pragma unroll
  for (int i = 0; i < 16; ++i) { acc0[i] = 0.0f; acc1[i] = 0.0f; }
  float rsum0 = 0.0f, rsum1 = 0.0f;

  // staging pointers (chunk 0), advanced by constant stride per chunk
  const u16* kp = k  + ((size_t)((b * L_ + srow) * H_ + h)) * DH_ + skoff;
  const u16* vp = vt + ((size_t)((b * H_ + h) * DH_ + srow)) * L_ + skoff;

  short8 rk[2], rv[2];             // chunk-0 K/V prefetch
#pragma unroll
  for (int it = 0; it < 2; ++it) {
    rk[it] = *(const short8*)(kp + (size_t)it * 32 * H_ * DH_);
    rv[it] = *(const short8*)(vp + (size_t)it * 32 * L_);
  }

  const float4* bp = (const float4*)(biasP + ((size_t)(qt * 4 + w) * 16) * 2048) + lane;

  for (int c = 0; c < 16; ++c) {
    __syncthreads();               // previous chunk readers done
#pragma unroll
    for (int it = 0; it < 2; ++it) {
      *(short8*)&lK[it * 32 + srow][skoff]  = rk[it];
      *(short8*)&lVt[it * 32 + srow][skoff] = rv[it];
    }
    __syncthreads();

    // S^T tiles: bias^T as accumulator init, loaded at use
    floatx16 s0, s1;
#pragma unroll
    for (int rr = 0; rr < 4; ++rr) {
      float4 b0 = bp[rr * 64];
      float4 b1 = bp[(4 + rr) * 64];
      s0[rr * 4 + 0] = b0.x; s0[rr * 4 + 1] = b0.y; s0[rr * 4 + 2] = b0.z; s0[rr * 4 + 3] = b0.w;
      s1[rr * 4 + 0] = b1.x; s1[rr * 4 + 1] = b1.y; s1[rr * 4 + 2] = b1.z; s1[rr * 4 + 3] = b1.w;
    }
    bp += 512;

    if (c < 15) {                  // register prefetch of chunk c+1 K/V
      kp += (size_t)64 * H_ * DH_;
      vp += 64;
#pragma unroll
      for (int it = 0; it < 2; ++it) {
        rk[it] = *(const short8*)(kp + (size_t)it * 32 * H_ * DH_);
        rv[it] = *(const short8*)(vp + (size_t)it * 32 * L_);
      }
    }

#pragma unroll
    for (int ks = 0; ks < 4; ++ks) {
      half8 bk0 = *(const half8*)&lK[c32][ks * 16 + hi * 8];
      half8 bk1 = *(const half8*)&lK[32 + c32][ks * 16 + hi * 8];
      s0 = __builtin_amdgcn_mfma_f32_32x32x16_f16(bk0, aq[ks], s0, 0, 0, 0);
      s1 = __builtin_amdgcn_mfma_f32_32x32x16_f16(bk1, aq[ks], s1, 0, 0, 0);
    }

    // softmax weights (exp2; shift folded into bias) -> in-register bf16 PV A-frags
    union { short8 v[4]; unsigned u[16]; } ap;
#pragma unroll
    for (int reg = 0; reg < 16; ++reg) {
      float p0 = EXP2(s0[reg]);
      float p1 = EXP2(s1[reg]);
      ap.u[reg] = pack_bf2(p0, p1);
      if (reg & 1) rsum1 += p0 + p1; else rsum0 += p0 + p1;
    }

    // O += P V (2 dh-tiles), bf16
#pragma unroll
    for (int ks = 0; ks < 4; ++ks) {
      short8 bv0 = *(const short8*)&lVt[c32][ks * 16 + hi * 8];
      short8 bv1 = *(const short8*)&lVt[32 + c32][ks * 16 + hi * 8];
      acc0 = __builtin_amdgcn_mfma_f32_32x32x16_bf16(ap.v[ks], bv0, acc0, 0, 0, 0);
      acc1 = __builtin_amdgcn_mfma_f32_32x32x16_bf16(ap.v[ks], bv1, acc1, 0, 0, 0);
    }
  }

  // rowsum: combine hi halves, broadcast via wave-private LDS.
  float rsum = rsum0 + rsum1;
  rsum += __shfl_xor(rsum, 32, 64);
  if (hi == 0) lRS[w][c32] = rsum;

  // epilogue: normalize (acc C-layout: row=(reg&3)+8*(reg>>2)+4*hi, col=dh=c32)
#pragma unroll
  for (int reg = 0; reg < 16; ++reg) {
    int rl = (reg & 3) + 8 * (reg >> 2) + 4 * hi;
    float inv = 1.0f / lRS[w][rl];
    int row = qr0 + rl;
    size_t obase = ((size_t)((b * L_ + row) * H_ + h)) * DH_;
    o[obase + c32]      = f2h(acc0[reg] * inv);
    o[obase + 32 + c32] = f2h(acc1[reg] * inv);
  }
}

// ---------------------------------------------------------------- launch
extern "C" void kernel_launch(void* const* d_in, const int* in_sizes, int n_in,
                              void* d_out, int out_size, void* d_ws, size_t ws_size,
                              hipStream_t stream) {
  const float* x    = (const float*)d_in[0];
  const float* mask = (const float*)d_in[1];
  const float* Wk   = (const float*)d_in[2];
  const float* Wv   = (const float*)d_in[3];
  const float* Wq   = (const float*)d_in[4];
  const float* Wo   = (const float*)d_in[5];

  char* ws = (char*)d_ws;
  u16* xf    = (u16*)(ws);                        // 16 MB x f16 ; later attn out f16
  u16* aout  = xf;
  u16* kf    = (u16*)(ws + (16ull << 20));        // 16 MB k f16
  u16* vtb   = (u16*)(ws + (32ull << 20));        // 16 MB transposed+permuted V bf16
  float* biasP = (float*)(ws + (48ull << 20));    // 4 MB permuted bias^T (log2e-scaled)
  u16* wqf   = (u16*)(ws + (52ull << 20));        // 2 MB each, f16 weights
  u16* wkf   = (u16*)(ws + (54ull << 20));
  u16* wvf   = (u16*)(ws + (56ull << 20));
  u16* wof   = (u16*)(ws + (58ull << 20));
  // d_out (32 MB): qf (lower 16) -> final fp32 out overwrites
  u16* qf = (u16*)d_out;

  cast_all<<<16384, 256, 0, stream>>>(x, Wq, Wk, Wv, Wo, mask,
                                      xf, wqf, wkf, wvf, wof, biasP);

  gemm_qkv<<<dim3(24, 64), 256, 0, stream>>>(xf, wqf, wkf, wvf, qf, kf, vtb);

  attn_kernel<<<dim3(B_ * H_, L_ / 128), 256, 0, stream>>>(qf, kf, vtb, biasP, aout);

  gemm_fin<<<dim3(D_ / 128, (B_ * L_) / 128), 256, 0, stream>>>(
      aout, wof, (float*)d_out, B_ * L_, D_, D_);
}

// Round 11
// 249.105 us; speedup vs baseline: 1.0466x; 1.0466x over previous
//
#include <hip/hip_runtime.h>

// Problem constants (B=8, L=1024, D=1024, H=16, DH=64)
#define B_  8
#define L_  1024
#define D_  1024
#define H_  16
#define DH_ 64

typedef unsigned short u16;
typedef __attribute__((ext_vector_type(8))) short short8;      // 8 x u16 bag (bf16)
typedef __attribute__((ext_vector_type(8))) _Float16 half8;    // 8 x f16
typedef __attribute__((ext_vector_type(4))) float floatx4;     // 16x16 C/D frag
typedef __attribute__((ext_vector_type(16))) float floatx16;   // 32x32 C/D frag

// fp32 -> bf16 round-to-nearest-even
static __device__ __forceinline__ u16 f2bf(float f) {
  union { float f; unsigned u; } cv; cv.f = f;
  unsigned u = cv.u;
  return (u16)((u + 0x7fffu + ((u >> 16) & 1u)) >> 16);
}
// fp32 -> f16 (RNE)
static __device__ __forceinline__ u16 f2h(float f) {
  union { _Float16 h; u16 u; } cv; cv.h = (_Float16)f; return cv.u;
}
// pack two fp32 -> two bf16 via v_perm; low u16 = a, high u16 = b
static __device__ __forceinline__ unsigned pack_bf2(float a, float b) {
  union { float f; unsigned u; } ua, ub; ua.f = a; ub.f = b;
  return __builtin_amdgcn_perm(ub.u + 0x8000u, ua.u + 0x8000u, 0x07060302u);
}

#if __has_builtin(__builtin_amdgcn_exp2f)
#define EXP2(x) __builtin_amdgcn_exp2f(x)
#else
#define EXP2(x) __expf((x) * 0.6931471805599453f)
#endif

// ---------------------------------------------------------------- fused casts + bias permute
// blocks [0,12288): cast x/Wq/Wk/Wv/Wo fp32 -> f16
// blocks [12288,16384): permuted bias^T table, PRE-MULTIPLIED by log2(e)
__global__ void cast_all(const float* __restrict__ x,  const float* __restrict__ wq,
                         const float* __restrict__ wk, const float* __restrict__ wv,
                         const float* __restrict__ wo, const float* __restrict__ mask,
                         u16* __restrict__ xf,  u16* __restrict__ wqf,
                         u16* __restrict__ wkf, u16* __restrict__ wvf,
                         u16* __restrict__ wof, float* __restrict__ biasP) {
  int blk = blockIdx.x;
  if (blk >= 12288) {
    int i = (blk - 12288) * 256 + threadIdx.x;
    int e = i & 3, lane = (i >> 2) & 63, rr = (i >> 8) & 3, t = (i >> 10) & 1;
    int c = (i >> 11) & 15, w = (i >> 15) & 3, qt = i >> 17;
    int kk  = e + 8 * rr + 4 * (lane >> 5);
    int row = qt * 128 + w * 32 + (lane & 31);
    int key = c * 64 + t * 32 + kk;
    // log2e * ((mask-1)*1.25e8 - 24)
    biasP[i] = (mask[(size_t)row * L_ + key] - 1.0f) * 1.8033688e8f - 34.624681f;
    return;
  }
  const float* src; u16* dst; int off;
  if (blk < 8192)       { src = x;  dst = xf;  off = blk; }
  else if (blk < 9216)  { src = wq; dst = wqf; off = blk - 8192; }
  else if (blk < 10240) { src = wk; dst = wkf; off = blk - 9216; }
  else if (blk < 11264) { src = wv; dst = wvf; off = blk - 10240; }
  else                  { src = wo; dst = wof; off = blk - 11264; }
  int i = off * 1024 + threadIdx.x * 4;
  float4 f = *(const float4*)(src + i);
  ushort4 r;
  r.x = f2h(f.x); r.y = f2h(f.y); r.z = f2h(f.z); r.w = f2h(f.w);
  *(ushort4*)(dst + i) = r;
}

// ---------------------------------------------------------------- LDS staging helper
typedef __attribute__((address_space(3))) void  lds_void;
typedef const __attribute__((address_space(1))) void g_void;
static __device__ __forceinline__ void load_lds16(const void* g, void* l) {
  __builtin_amdgcn_global_load_lds((g_void*)g, (lds_void*)l, 16, 0, 0);
}

// ---------------------------------------------------------------- fused QKV GEMM (BT), f16 inputs
// grid (24, 64): n-blocks 0-7 -> q (scale 1/8*log2e, f16), 8-15 -> k (f16),
// 16-23 -> v (bf16, transposed+key-permuted vt layout via an LDS roundtrip
// whose tile uses ROW STRIDE 130 u16: bank = (row + col/2) % 32, so the
// column-gather reads are 2-way (free) instead of the stride-128 8-way that
// cost 1.05M conflict cycles in the r9 version).
// K-loop: LDS double-buffered BK=32 tiles, counted vmcnt(4), chunk-XOR swizzle
// (PMC-verified 0 bank conflicts). 682 TF.
__global__ __launch_bounds__(256) void gemm_qkv(const u16* __restrict__ A,
                                                const u16* __restrict__ wq,
                                                const u16* __restrict__ wk,
                                                const u16* __restrict__ wv,
                                                u16* __restrict__ qf,
                                                u16* __restrict__ kf,
                                                u16* __restrict__ vt) {
  const int K = D_, N = D_;
  int nb = blockIdx.x;
  const u16* Bw; u16* Cp; float scale; int obf;
  if (nb < 8)       { Bw = wq; Cp = qf; scale = 0.18033688f; obf = 0; }  // 0.125*log2e
  else if (nb < 16) { Bw = wk; Cp = kf; scale = 1.0f;        obf = 0; }
  else              { Bw = wv; Cp = vt; scale = 1.0f;        obf = 1; }
  const int n0 = (nb & 7) * 128;

  // pool: first 16384 = staging (lA 8192 | lB 8192); as 128x130 transpose tile
  // for the V epilogue it needs 128*130 = 16640.
  __shared__ u16 pool[16640];
  u16* lA = pool;
  u16* lB = pool + 8192;
  const int tid  = threadIdx.x;
  const int w    = tid >> 6;
  const int lane = tid & 63;
  const int m    = lane & 15;
  const int kg   = lane >> 4;
  const int m0   = blockIdx.y * 128;
  const int wm   = (w >> 1) * 64;
  const int wn   = (w & 1) * 64;
  const int rowS = tid >> 2;
  const int part = tid & 3;
  // swizzle: stored chunk c' holds global chunk c' ^ ((row>>1)&3)
  const int csrc8 = ((part ^ ((rowS >> 1) & 3))) * 8;   // staging source column
  const int kgs   = (kg ^ ((m >> 1) & 3)) * 8;          // fragment read column

  floatx4 acc[4][4];
#pragma unroll
  for (int i = 0; i < 4; ++i)
#pragma unroll
    for (int j = 0; j < 4; ++j)
#pragma unroll
      for (int r = 0; r < 4; ++r) acc[i][j][r] = 0.0f;

  auto STAGE = [&](int k0, int bufsel) {
#pragma unroll
    for (int rnd = 0; rnd < 2; ++rnd) {
      const u16* ga = A  + (size_t)(m0 + rnd * 64 + rowS) * K + k0 + csrc8;
      const u16* gb = Bw + (size_t)(n0 + rnd * 64 + rowS) * K + k0 + csrc8;
      load_lds16(ga, lA + bufsel * 4096 + rnd * 2048 + w * 512);
      load_lds16(gb, lB + bufsel * 4096 + rnd * 2048 + w * 512);
    }
  };

  STAGE(0, 0);
  STAGE(32, 1);

  for (int k0 = 0; k0 < K; k0 += 32) {
    const int buf = (k0 >> 5) & 1;
    if (k0 + 32 < K) { asm volatile("s_waitcnt vmcnt(4)" ::: "memory"); }
    else             { asm volatile("s_waitcnt vmcnt(0)" ::: "memory"); }
    __builtin_amdgcn_s_barrier();
    __builtin_amdgcn_sched_barrier(0);

    const u16* pA = lA + buf * 4096;
    const u16* pB = lB + buf * 4096;
    half8 af[4], bf[4];
#pragma unroll
    for (int i = 0; i < 4; ++i) af[i] = *(const half8*)&pA[(wm + i * 16 + m) * 32 + kgs];
#pragma unroll
    for (int i = 0; i < 4; ++i) bf[i] = *(const half8*)&pB[(wn + i * 16 + m) * 32 + kgs];
#pragma unroll
    for (int mi = 0; mi < 4; ++mi)
#pragma unroll
      for (int ni = 0; ni < 4; ++ni)
        acc[mi][ni] = __builtin_amdgcn_mfma_f32_16x16x32_f16(af[mi], bf[ni], acc[mi][ni], 0, 0, 0);

    __builtin_amdgcn_sched_barrier(0);
    __builtin_amdgcn_s_barrier();
    if (k0 + 64 < K) STAGE(k0 + 64, buf);
  }

  if (!obf) {
    // q/k: normal f16 store
#pragma unroll
    for (int mi = 0; mi < 4; ++mi)
#pragma unroll
      for (int ni = 0; ni < 4; ++ni)
#pragma unroll
        for (int r = 0; r < 4; ++r) {
          int row = m0 + wm + mi * 16 + kg * 4 + r;
          int col = n0 + wn + ni * 16 + m;
          Cp[(size_t)row * N + col] = f2h(acc[mi][ni][r] * scale);
        }
  } else {
    // V: bf16 tile -> LDS (128 rows x stride 130) -> transposed+permuted store.
    // After the K-loop's final barrier all LDS reads are done; pool is free.
#pragma unroll
    for (int mi = 0; mi < 4; ++mi)
#pragma unroll
      for (int ni = 0; ni < 4; ++ni)
#pragma unroll
        for (int r = 0; r < 4; ++r) {
          int rl = wm + mi * 16 + kg * 4 + r;      // 0..127 local row (l - m0)
          int cl = wn + ni * 16 + m;               // 0..127 local col (e - n0)
          pool[rl * 130 + cl] = f2bf(acc[mi][ni][r]);
        }
    __syncthreads();
    const int b  = m0 >> 10;                       // batch of this 128-row strip
    const int l0 = m0 & 1023;                      // row offset within sequence
    const int h0 = (nb & 7) * 2;                   // first head of this col strip
    const int j  = tid >> 2;                       // dh (0..63)
    const int p0 = (tid & 3) * 16;                 // position base
#pragma unroll
    for (int hh = 0; hh < 2; ++hh) {
#pragma unroll
      for (int cc = 0; cc < 2; ++cc) {
        __attribute__((aligned(16))) u16 tmp[16];
#pragma unroll
        for (int s = 0; s < 16; ++s) {
          int p   = p0 + s;
          int l64 = (p >> 1) + ((p & 1) << 5);     // key within 64-chunk at pos p
          tmp[s] = pool[(cc * 64 + l64) * 130 + hh * 64 + j];
        }
        u16* dst = vt + ((size_t)((b * H_ + h0 + hh) * DH_ + j)) * L_ + l0 + cc * 64 + p0;
        *(short8*)(dst)     = *(const short8*)&tmp[0];
        *(short8*)(dst + 8) = *(const short8*)&tmp[8];
      }
    }
  }
}

// ---------------------------------------------------------------- final GEMM (BT), f16 in, fp32 out
__global__ __launch_bounds__(256) void gemm_fin(const u16* __restrict__ A,
                                                const u16* __restrict__ Bw,
                                                float* __restrict__ Cp,
                                                int M, int N, int K) {
  __shared__ u16 lA[2 * 128 * 32];
  __shared__ u16 lB[2 * 128 * 32];
  const int tid  = threadIdx.x;
  const int w    = tid >> 6;
  const int lane = tid & 63;
  const int m    = lane & 15;
  const int kg   = lane >> 4;
  const int m0   = blockIdx.y * 128;
  const int n0   = blockIdx.x * 128;
  const int wm   = (w >> 1) * 64;
  const int wn   = (w & 1) * 64;
  const int rowS = tid >> 2;
  const int part = tid & 3;
  const int csrc8 = ((part ^ ((rowS >> 1) & 3))) * 8;
  const int kgs   = (kg ^ ((m >> 1) & 3)) * 8;

  floatx4 acc[4][4];
#pragma unroll
  for (int i = 0; i < 4; ++i)
#pragma unroll
    for (int j = 0; j < 4; ++j)
#pragma unroll
      for (int r = 0; r < 4; ++r) acc[i][j][r] = 0.0f;

  auto STAGE = [&](int k0, int bufsel) {
#pragma unroll
    for (int rnd = 0; rnd < 2; ++rnd) {
      const u16* ga = A  + (size_t)(m0 + rnd * 64 + rowS) * K + k0 + csrc8;
      const u16* gb = Bw + (size_t)(n0 + rnd * 64 + rowS) * K + k0 + csrc8;
      load_lds16(ga, lA + bufsel * 4096 + rnd * 2048 + w * 512);
      load_lds16(gb, lB + bufsel * 4096 + rnd * 2048 + w * 512);
    }
  };

  STAGE(0, 0);
  STAGE(32, 1);

  for (int k0 = 0; k0 < K; k0 += 32) {
    const int buf = (k0 >> 5) & 1;
    if (k0 + 32 < K) { asm volatile("s_waitcnt vmcnt(4)" ::: "memory"); }
    else             { asm volatile("s_waitcnt vmcnt(0)" ::: "memory"); }
    __builtin_amdgcn_s_barrier();
    __builtin_amdgcn_sched_barrier(0);

    const u16* pA = lA + buf * 4096;
    const u16* pB = lB + buf * 4096;
    half8 af[4], bf[4];
#pragma unroll
    for (int i = 0; i < 4; ++i) af[i] = *(const half8*)&pA[(wm + i * 16 + m) * 32 + kgs];
#pragma unroll
    for (int i = 0; i < 4; ++i) bf[i] = *(const half8*)&pB[(wn + i * 16 + m) * 32 + kgs];
#pragma unroll
    for (int mi = 0; mi < 4; ++mi)
#pragma unroll
      for (int ni = 0; ni < 4; ++ni)
        acc[mi][ni] = __builtin_amdgcn_mfma_f32_16x16x32_f16(af[mi], bf[ni], acc[mi][ni], 0, 0, 0);

    __builtin_amdgcn_sched_barrier(0);
    __builtin_amdgcn_s_barrier();
    if (k0 + 64 < K) STAGE(k0 + 64, buf);
  }

#pragma unroll
  for (int mi = 0; mi < 4; ++mi)
#pragma unroll
    for (int ni = 0; ni < 4; ++ni)
#pragma unroll
      for (int r = 0; r < 4; ++r) {
        int row = m0 + wm + mi * 16 + kg * 4 + r;
        int col = n0 + wn + ni * 16 + m;
        Cp[(size_t)row * N + col] = acc[mi][ni][r];
      }
}

// ---------------------------------------------------------------- fused flash attention, 32x32 MFMA
// grid (bh=128, qt=8). 4 waves x 32 q-rows = 128 rows/block. 64-key chunks.
// Round-4 proven version (register diet, <=128 regs, 4 waves/SIMD).
__global__ __launch_bounds__(256, 4) void attn_kernel(const u16* __restrict__ q,
                                                      const u16* __restrict__ k,
                                                      const u16* __restrict__ vt,
                                                      const float* __restrict__ biasP,
                                                      u16* __restrict__ o) {
  __shared__ u16 lK[64][72];       // f16, [key][dh]
  __shared__ u16 lVt[64][72];      // bf16, [dh][pos] (permuted keys)
  __shared__ float lRS[4][32];     // per-wave rowsum broadcast

  const int bh = blockIdx.x, qt = blockIdx.y;
  const int b = bh >> 4, h = bh & 15;
  const int tid = threadIdx.x;
  const int w = tid >> 6, lane = tid & 63;
  const int c32 = lane & 31, hi = lane >> 5;
  const int qr0 = qt * 128 + w * 32;

  const int srow  = tid >> 3;      // 0..31 (stages 2 rows via it)
  const int skoff = (tid & 7) * 8;

  // Q B-frags: lane holds Q[q=qr0+c32][dh-slice ks*16+hi*8]
  const size_t qbase = ((size_t)((b * L_ + qr0 + c32) * H_ + h)) * DH_;
  half8 aq[4];
#pragma unroll
  for (int ks = 0; ks < 4; ++ks)
    aq[ks] = *(const half8*)(q + qbase + ks * 16 + hi * 8);

  floatx16 acc0, acc1;
#pragma unroll
  for (int i = 0; i < 16; ++i) { acc0[i] = 0.0f; acc1[i] = 0.0f; }
  float rsum0 = 0.0f, rsum1 = 0.0f;

  // staging pointers (chunk 0), advanced by constant stride per chunk
  const u16* kp = k  + ((size_t)((b * L_ + srow) * H_ + h)) * DH_ + skoff;
  const u16* vp = vt + ((size_t)((b * H_ + h) * DH_ + srow)) * L_ + skoff;

  short8 rk[2], rv[2];             // chunk-0 K/V prefetch
#pragma unroll
  for (int it = 0; it < 2; ++it) {
    rk[it] = *(const short8*)(kp + (size_t)it * 32 * H_ * DH_);
    rv[it] = *(const short8*)(vp + (size_t)it * 32 * L_);
  }

  const float4* bp = (const float4*)(biasP + ((size_t)(qt * 4 + w) * 16) * 2048) + lane;

  for (int c = 0; c < 16; ++c) {
    __syncthreads();               // previous chunk readers done
#pragma unroll
    for (int it = 0; it < 2; ++it) {
      *(short8*)&lK[it * 32 + srow][skoff]  = rk[it];
      *(short8*)&lVt[it * 32 + srow][skoff] = rv[it];
    }
    __syncthreads();

    // S^T tiles: bias^T as accumulator init, loaded at use
    floatx16 s0, s1;
#pragma unroll
    for (int rr = 0; rr < 4; ++rr) {
      float4 b0 = bp[rr * 64];
      float4 b1 = bp[(4 + rr) * 64];
      s0[rr * 4 + 0] = b0.x; s0[rr * 4 + 1] = b0.y; s0[rr * 4 + 2] = b0.z; s0[rr * 4 + 3] = b0.w;
      s1[rr * 4 + 0] = b1.x; s1[rr * 4 + 1] = b1.y; s1[rr * 4 + 2] = b1.z; s1[rr * 4 + 3] = b1.w;
    }
    bp += 512;

    if (c < 15) {                  // register prefetch of chunk c+1 K/V
      kp += (size_t)64 * H_ * DH_;
      vp += 64;
#pragma unroll
      for (int it = 0; it < 2; ++it) {
        rk[it] = *(const short8*)(kp + (size_t)it * 32 * H_ * DH_);
        rv[it] = *(const short8*)(vp + (size_t)it * 32 * L_);
      }
    }

#pragma unroll
    for (int ks = 0; ks < 4; ++ks) {
      half8 bk0 = *(const half8*)&lK[c32][ks * 16 + hi * 8];
      half8 bk1 = *(const half8*)&lK[32 + c32][ks * 16 + hi * 8];
      s0 = __builtin_amdgcn_mfma_f32_32x32x16_f16(bk0, aq[ks], s0, 0, 0, 0);
      s1 = __builtin_amdgcn_mfma_f32_32x32x16_f16(bk1, aq[ks], s1, 0, 0, 0);
    }

    // softmax weights (exp2; shift folded into bias) -> in-register bf16 PV A-frags
    union { short8 v[4]; unsigned u[16]; } ap;
#pragma unroll
    for (int reg = 0; reg < 16; ++reg) {
      float p0 = EXP2(s0[reg]);
      float p1 = EXP2(s1[reg]);
      ap.u[reg] = pack_bf2(p0, p1);
      if (reg & 1) rsum1 += p0 + p1; else rsum0 += p0 + p1;
    }

    // O += P V (2 dh-tiles), bf16
#pragma unroll
    for (int ks = 0; ks < 4; ++ks) {
      short8 bv0 = *(const short8*)&lVt[c32][ks * 16 + hi * 8];
      short8 bv1 = *(const short8*)&lVt[32 + c32][ks * 16 + hi * 8];
      acc0 = __builtin_amdgcn_mfma_f32_32x32x16_bf16(ap.v[ks], bv0, acc0, 0, 0, 0);
      acc1 = __builtin_amdgcn_mfma_f32_32x32x16_bf16(ap.v[ks], bv1, acc1, 0, 0, 0);
    }
  }

  // rowsum: combine hi halves, broadcast via wave-private LDS.
  float rsum = rsum0 + rsum1;
  rsum += __shfl_xor(rsum, 32, 64);
  if (hi == 0) lRS[w][c32] = rsum;

  // epilogue: normalize (acc C-layout: row=(reg&3)+8*(reg>>2)+4*hi, col=dh=c32)
#pragma unroll
  for (int reg = 0; reg < 16; ++reg) {
    int rl = (reg & 3) + 8 * (reg >> 2) + 4 * hi;
    float inv = 1.0f / lRS[w][rl];
    int row = qr0 + rl;
    size_t obase = ((size_t)((b * L_ + row) * H_ + h)) * DH_;
    o[obase + c32]      = f2h(acc0[reg] * inv);
    o[obase + 32 + c32] = f2h(acc1[reg] * inv);
  }
}

// ---------------------------------------------------------------- launch
extern "C" void kernel_launch(void* const* d_in, const int* in_sizes, int n_in,
                              void* d_out, int out_size, void* d_ws, size_t ws_size,
                              hipStream_t stream) {
  const float* x    = (const float*)d_in[0];
  const float* mask = (const float*)d_in[1];
  const float* Wk   = (const float*)d_in[2];
  const float* Wv   = (const float*)d_in[3];
  const float* Wq   = (const float*)d_in[4];
  const float* Wo   = (const float*)d_in[5];

  char* ws = (char*)d_ws;
  u16* xf    = (u16*)(ws);                        // 16 MB x f16 ; later attn out f16
  u16* aout  = xf;
  u16* kf    = (u16*)(ws + (16ull << 20));        // 16 MB k f16
  u16* vtb   = (u16*)(ws + (32ull << 20));        // 16 MB transposed+permuted V bf16
  float* biasP = (float*)(ws + (48ull << 20));    // 4 MB permuted bias^T (log2e-scaled)
  u16* wqf   = (u16*)(ws + (52ull << 20));        // 2 MB each, f16 weights
  u16* wkf   = (u16*)(ws + (54ull << 20));
  u16* wvf   = (u16*)(ws + (56ull << 20));
  u16* wof   = (u16*)(ws + (58ull << 20));
  // d_out (32 MB): qf (lower 16) -> final fp32 out overwrites
  u16* qf = (u16*)d_out;

  cast_all<<<16384, 256, 0, stream>>>(x, Wq, Wk, Wv, Wo, mask,
                                      xf, wqf, wkf, wvf, wof, biasP);

  gemm_qkv<<<dim3(24, 64), 256, 0, stream>>>(xf, wqf, wkf, wvf, qf, kf, vtb);

  attn_kernel<<<dim3(B_ * H_, L_ / 128), 256, 0, stream>>>(qf, kf, vtb, biasP, aout);

  gemm_fin<<<dim3(D_ / 128, (B_ * L_) / 128), 256, 0, stream>>>(
      aout, wof, (float*)d_out, B_ * L_, D_, D_);
}

// Round 12
// 246.462 us; speedup vs baseline: 1.0578x; 1.0107x over previous
//
#include <hip/hip_runtime.h>

// Problem constants (B=8, L=1024, D=1024, H=16, DH=64)
#define B_  8
#define L_  1024
#define D_  1024
#define H_  16
#define DH_ 64

typedef unsigned short u16;
typedef __attribute__((ext_vector_type(8))) short short8;      // 8 x u16 bag (bf16)
typedef __attribute__((ext_vector_type(8))) _Float16 half8;    // 8 x f16
typedef __attribute__((ext_vector_type(4))) float floatx4;     // 16x16 C/D frag
typedef __attribute__((ext_vector_type(16))) float floatx16;   // 32x32 C/D frag

// fp32 -> bf16 round-to-nearest-even
static __device__ __forceinline__ u16 f2bf(float f) {
  union { float f; unsigned u; } cv; cv.f = f;
  unsigned u = cv.u;
  return (u16)((u + 0x7fffu + ((u >> 16) & 1u)) >> 16);
}
// fp32 -> f16 (RNE)
static __device__ __forceinline__ u16 f2h(float f) {
  union { _Float16 h; u16 u; } cv; cv.h = (_Float16)f; return cv.u;
}
// pack two fp32 -> two bf16 via v_perm; low u16 = a, high u16 = b
static __device__ __forceinline__ unsigned pack_bf2(float a, float b) {
  union { float f; unsigned u; } ua, ub; ua.f = a; ub.f = b;
  return __builtin_amdgcn_perm(ub.u + 0x8000u, ua.u + 0x8000u, 0x07060302u);
}

#if __has_builtin(__builtin_amdgcn_exp2f)
#define EXP2(x) __builtin_amdgcn_exp2f(x)
#else
#define EXP2(x) __expf((x) * 0.6931471805599453f)
#endif

// ---------------------------------------------------------------- fused casts + bias permute
// blocks [0,12288): cast x/Wq/Wk/Wv/Wo fp32 -> f16
// blocks [12288,16384): permuted bias^T table, PRE-MULTIPLIED by log2(e)
__global__ void cast_all(const float* __restrict__ x,  const float* __restrict__ wq,
                         const float* __restrict__ wk, const float* __restrict__ wv,
                         const float* __restrict__ wo, const float* __restrict__ mask,
                         u16* __restrict__ xf,  u16* __restrict__ wqf,
                         u16* __restrict__ wkf, u16* __restrict__ wvf,
                         u16* __restrict__ wof, float* __restrict__ biasP) {
  int blk = blockIdx.x;
  if (blk >= 12288) {
    int i = (blk - 12288) * 256 + threadIdx.x;
    int e = i & 3, lane = (i >> 2) & 63, rr = (i >> 8) & 3, t = (i >> 10) & 1;
    int c = (i >> 11) & 15, w = (i >> 15) & 3, qt = i >> 17;
    int kk  = e + 8 * rr + 4 * (lane >> 5);
    int row = qt * 128 + w * 32 + (lane & 31);
    int key = c * 64 + t * 32 + kk;
    // log2e * ((mask-1)*1.25e8 - 24)
    biasP[i] = (mask[(size_t)row * L_ + key] - 1.0f) * 1.8033688e8f - 34.624681f;
    return;
  }
  const float* src; u16* dst; int off;
  if (blk < 8192)       { src = x;  dst = xf;  off = blk; }
  else if (blk < 9216)  { src = wq; dst = wqf; off = blk - 8192; }
  else if (blk < 10240) { src = wk; dst = wkf; off = blk - 9216; }
  else if (blk < 11264) { src = wv; dst = wvf; off = blk - 10240; }
  else                  { src = wo; dst = wof; off = blk - 11264; }
  int i = off * 1024 + threadIdx.x * 4;
  float4 f = *(const float4*)(src + i);
  ushort4 r;
  r.x = f2h(f.x); r.y = f2h(f.y); r.z = f2h(f.z); r.w = f2h(f.w);
  *(ushort4*)(dst + i) = r;
}

// ---------------------------------------------------------------- LDS staging helper
typedef __attribute__((address_space(3))) void  lds_void;
typedef const __attribute__((address_space(1))) void g_void;
static __device__ __forceinline__ void load_lds16(const void* g, void* l) {
  __builtin_amdgcn_global_load_lds((g_void*)g, (lds_void*)l, 16, 0, 0);
}

// ---------------------------------------------------------------- fused QKV GEMM (BT), f16 inputs
// grid (24, 64): n-blocks 0-7 -> q (scale 1/8*log2e, f16), 8-15 -> k (f16),
// 16-23 -> v (bf16, transposed+key-permuted vt layout via an LDS roundtrip,
// row stride 130 u16 -> column-gather reads are 2-way/free; r11 PMC:
// conflicts 1.05M -> 262K, 73.1 us).
// K-loop: LDS double-buffered BK=32 tiles, counted vmcnt(4), chunk-XOR swizzle.
__global__ __launch_bounds__(256) void gemm_qkv(const u16* __restrict__ A,
                                                const u16* __restrict__ wq,
                                                const u16* __restrict__ wk,
                                                const u16* __restrict__ wv,
                                                u16* __restrict__ qf,
                                                u16* __restrict__ kf,
                                                u16* __restrict__ vt) {
  const int K = D_, N = D_;
  int nb = blockIdx.x;
  const u16* Bw; u16* Cp; float scale; int obf;
  if (nb < 8)       { Bw = wq; Cp = qf; scale = 0.18033688f; obf = 0; }  // 0.125*log2e
  else if (nb < 16) { Bw = wk; Cp = kf; scale = 1.0f;        obf = 0; }
  else              { Bw = wv; Cp = vt; scale = 1.0f;        obf = 1; }
  const int n0 = (nb & 7) * 128;

  // pool: first 16384 = staging (lA 8192 | lB 8192); as 128x130 transpose tile
  // for the V epilogue it needs 128*130 = 16640.
  __shared__ u16 pool[16640];
  u16* lA = pool;
  u16* lB = pool + 8192;
  const int tid  = threadIdx.x;
  const int w    = tid >> 6;
  const int lane = tid & 63;
  const int m    = lane & 15;
  const int kg   = lane >> 4;
  const int m0   = blockIdx.y * 128;
  const int wm   = (w >> 1) * 64;
  const int wn   = (w & 1) * 64;
  const int rowS = tid >> 2;
  const int part = tid & 3;
  // swizzle: stored chunk c' holds global chunk c' ^ ((row>>1)&3)
  const int csrc8 = ((part ^ ((rowS >> 1) & 3))) * 8;   // staging source column
  const int kgs   = (kg ^ ((m >> 1) & 3)) * 8;          // fragment read column

  floatx4 acc[4][4];
#pragma unroll
  for (int i = 0; i < 4; ++i)
#pragma unroll
    for (int j = 0; j < 4; ++j)
#pragma unroll
      for (int r = 0; r < 4; ++r) acc[i][j][r] = 0.0f;

  auto STAGE = [&](int k0, int bufsel) {
#pragma unroll
    for (int rnd = 0; rnd < 2; ++rnd) {
      const u16* ga = A  + (size_t)(m0 + rnd * 64 + rowS) * K + k0 + csrc8;
      const u16* gb = Bw + (size_t)(n0 + rnd * 64 + rowS) * K + k0 + csrc8;
      load_lds16(ga, lA + bufsel * 4096 + rnd * 2048 + w * 512);
      load_lds16(gb, lB + bufsel * 4096 + rnd * 2048 + w * 512);
    }
  };

  STAGE(0, 0);
  STAGE(32, 1);

  for (int k0 = 0; k0 < K; k0 += 32) {
    const int buf = (k0 >> 5) & 1;
    if (k0 + 32 < K) { asm volatile("s_waitcnt vmcnt(4)" ::: "memory"); }
    else             { asm volatile("s_waitcnt vmcnt(0)" ::: "memory"); }
    __builtin_amdgcn_s_barrier();
    __builtin_amdgcn_sched_barrier(0);

    const u16* pA = lA + buf * 4096;
    const u16* pB = lB + buf * 4096;
    half8 af[4], bf[4];
#pragma unroll
    for (int i = 0; i < 4; ++i) af[i] = *(const half8*)&pA[(wm + i * 16 + m) * 32 + kgs];
#pragma unroll
    for (int i = 0; i < 4; ++i) bf[i] = *(const half8*)&pB[(wn + i * 16 + m) * 32 + kgs];
#pragma unroll
    for (int mi = 0; mi < 4; ++mi)
#pragma unroll
      for (int ni = 0; ni < 4; ++ni)
        acc[mi][ni] = __builtin_amdgcn_mfma_f32_16x16x32_f16(af[mi], bf[ni], acc[mi][ni], 0, 0, 0);

    __builtin_amdgcn_sched_barrier(0);
    __builtin_amdgcn_s_barrier();
    if (k0 + 64 < K) STAGE(k0 + 64, buf);
  }

  if (!obf) {
    // q/k: normal f16 store
#pragma unroll
    for (int mi = 0; mi < 4; ++mi)
#pragma unroll
      for (int ni = 0; ni < 4; ++ni)
#pragma unroll
        for (int r = 0; r < 4; ++r) {
          int row = m0 + wm + mi * 16 + kg * 4 + r;
          int col = n0 + wn + ni * 16 + m;
          Cp[(size_t)row * N + col] = f2h(acc[mi][ni][r] * scale);
        }
  } else {
    // V: bf16 tile -> LDS (128 rows x stride 130) -> transposed+permuted store.
#pragma unroll
    for (int mi = 0; mi < 4; ++mi)
#pragma unroll
      for (int ni = 0; ni < 4; ++ni)
#pragma unroll
        for (int r = 0; r < 4; ++r) {
          int rl = wm + mi * 16 + kg * 4 + r;      // 0..127 local row (l - m0)
          int cl = wn + ni * 16 + m;               // 0..127 local col (e - n0)
          pool[rl * 130 + cl] = f2bf(acc[mi][ni][r]);
        }
    __syncthreads();
    const int b  = m0 >> 10;                       // batch of this 128-row strip
    const int l0 = m0 & 1023;                      // row offset within sequence
    const int h0 = (nb & 7) * 2;                   // first head of this col strip
    const int j  = tid >> 2;                       // dh (0..63)
    const int p0 = (tid & 3) * 16;                 // position base
#pragma unroll
    for (int hh = 0; hh < 2; ++hh) {
#pragma unroll
      for (int cc = 0; cc < 2; ++cc) {
        __attribute__((aligned(16))) u16 tmp[16];
#pragma unroll
        for (int s = 0; s < 16; ++s) {
          int p   = p0 + s;
          int l64 = (p >> 1) + ((p & 1) << 5);     // key within 64-chunk at pos p
          tmp[s] = pool[(cc * 64 + l64) * 130 + hh * 64 + j];
        }
        u16* dst = vt + ((size_t)((b * H_ + h0 + hh) * DH_ + j)) * L_ + l0 + cc * 64 + p0;
        *(short8*)(dst)     = *(const short8*)&tmp[0];
        *(short8*)(dst + 8) = *(const short8*)&tmp[8];
      }
    }
  }
}

// ---------------------------------------------------------------- final GEMM (BT), f16 in, fp32 out
__global__ __launch_bounds__(256) void gemm_fin(const u16* __restrict__ A,
                                                const u16* __restrict__ Bw,
                                                float* __restrict__ Cp,
                                                int M, int N, int K) {
  __shared__ u16 lA[2 * 128 * 32];
  __shared__ u16 lB[2 * 128 * 32];
  const int tid  = threadIdx.x;
  const int w    = tid >> 6;
  const int lane = tid & 63;
  const int m    = lane & 15;
  const int kg   = lane >> 4;
  const int m0   = blockIdx.y * 128;
  const int n0   = blockIdx.x * 128;
  const int wm   = (w >> 1) * 64;
  const int wn   = (w & 1) * 64;
  const int rowS = tid >> 2;
  const int part = tid & 3;
  const int csrc8 = ((part ^ ((rowS >> 1) & 3))) * 8;
  const int kgs   = (kg ^ ((m >> 1) & 3)) * 8;

  floatx4 acc[4][4];
#pragma unroll
  for (int i = 0; i < 4; ++i)
#pragma unroll
    for (int j = 0; j < 4; ++j)
#pragma unroll
      for (int r = 0; r < 4; ++r) acc[i][j][r] = 0.0f;

  auto STAGE = [&](int k0, int bufsel) {
#pragma unroll
    for (int rnd = 0; rnd < 2; ++rnd) {
      const u16* ga = A  + (size_t)(m0 + rnd * 64 + rowS) * K + k0 + csrc8;
      const u16* gb = Bw + (size_t)(n0 + rnd * 64 + rowS) * K + k0 + csrc8;
      load_lds16(ga, lA + bufsel * 4096 + rnd * 2048 + w * 512);
      load_lds16(gb, lB + bufsel * 4096 + rnd * 2048 + w * 512);
    }
  };

  STAGE(0, 0);
  STAGE(32, 1);

  for (int k0 = 0; k0 < K; k0 += 32) {
    const int buf = (k0 >> 5) & 1;
    if (k0 + 32 < K) { asm volatile("s_waitcnt vmcnt(4)" ::: "memory"); }
    else             { asm volatile("s_waitcnt vmcnt(0)" ::: "memory"); }
    __builtin_amdgcn_s_barrier();
    __builtin_amdgcn_sched_barrier(0);

    const u16* pA = lA + buf * 4096;
    const u16* pB = lB + buf * 4096;
    half8 af[4], bf[4];
#pragma unroll
    for (int i = 0; i < 4; ++i) af[i] = *(const half8*)&pA[(wm + i * 16 + m) * 32 + kgs];
#pragma unroll
    for (int i = 0; i < 4; ++i) bf[i] = *(const half8*)&pB[(wn + i * 16 + m) * 32 + kgs];
#pragma unroll
    for (int mi = 0; mi < 4; ++mi)
#pragma unroll
      for (int ni = 0; ni < 4; ++ni)
        acc[mi][ni] = __builtin_amdgcn_mfma_f32_16x16x32_f16(af[mi], bf[ni], acc[mi][ni], 0, 0, 0);

    __builtin_amdgcn_sched_barrier(0);
    __builtin_amdgcn_s_barrier();
    if (k0 + 64 < K) STAGE(k0 + 64, buf);
  }

#pragma unroll
  for (int mi = 0; mi < 4; ++mi)
#pragma unroll
    for (int ni = 0; ni < 4; ++ni)
#pragma unroll
      for (int r = 0; r < 4; ++r) {
        int row = m0 + wm + mi * 16 + kg * 4 + r;
        int col = n0 + wn + ni * 16 + m;
        Cp[(size_t)row * N + col] = acc[mi][ni][r];
      }
}

// ---------------------------------------------------------------- fused flash attention, 32x32 MFMA
// grid (128, 8) flat-remapped so each XCD owns 16 consecutive bh values:
// per-XCD K/V footprint = 16 x 256 KB = 4 MB = one XCD L2 (T1, L2-residency).
// Round-4 register-diet body (<=128 regs, 4 waves/SIMD).
__global__ __launch_bounds__(256, 4) void attn_kernel(const u16* __restrict__ q,
                                                      const u16* __restrict__ k,
                                                      const u16* __restrict__ vt,
                                                      const float* __restrict__ biasP,
                                                      u16* __restrict__ o) {
  __shared__ u16 lK[64][72];       // f16, [key][dh]
  __shared__ u16 lVt[64][72];      // bf16, [dh][pos] (permuted keys)
  __shared__ float lRS[4][32];     // per-wave rowsum broadcast

  // XCD-grouping remap (bijective): assumes round-robin flat->XCD dispatch.
  // xcd = flat&7 owns bh in [xcd*16, xcd*16+16) for all qt.
  const int flat = blockIdx.y * 128 + blockIdx.x;
  const int idx  = flat >> 3;
  const int bh   = ((flat & 7) << 4) | (idx & 15);
  const int qt   = idx >> 4;

  const int b = bh >> 4, h = bh & 15;
  const int tid = threadIdx.x;
  const int w = tid >> 6, lane = tid & 63;
  const int c32 = lane & 31, hi = lane >> 5;
  const int qr0 = qt * 128 + w * 32;

  const int srow  = tid >> 3;      // 0..31 (stages 2 rows via it)
  const int skoff = (tid & 7) * 8;

  // Q B-frags: lane holds Q[q=qr0+c32][dh-slice ks*16+hi*8]
  const size_t qbase = ((size_t)((b * L_ + qr0 + c32) * H_ + h)) * DH_;
  half8 aq[4];
#pragma unroll
  for (int ks = 0; ks < 4; ++ks)
    aq[ks] = *(const half8*)(q + qbase + ks * 16 + hi * 8);

  floatx16 acc0, acc1;
#pragma unroll
  for (int i = 0; i < 16; ++i) { acc0[i] = 0.0f; acc1[i] = 0.0f; }
  float rsum0 = 0.0f, rsum1 = 0.0f;

  // staging pointers (chunk 0), advanced by constant stride per chunk
  const u16* kp = k  + ((size_t)((b * L_ + srow) * H_ + h)) * DH_ + skoff;
  const u16* vp = vt + ((size_t)((b * H_ + h) * DH_ + srow)) * L_ + skoff;

  short8 rk[2], rv[2];             // chunk-0 K/V prefetch
#pragma unroll
  for (int it = 0; it < 2; ++it) {
    rk[it] = *(const short8*)(kp + (size_t)it * 32 * H_ * DH_);
    rv[it] = *(const short8*)(vp + (size_t)it * 32 * L_);
  }

  const float4* bp = (const float4*)(biasP + ((size_t)(qt * 4 + w) * 16) * 2048) + lane;

  for (int c = 0; c < 16; ++c) {
    __syncthreads();               // previous chunk readers done
#pragma unroll
    for (int it = 0; it < 2; ++it) {
      *(short8*)&lK[it * 32 + srow][skoff]  = rk[it];
      *(short8*)&lVt[it * 32 + srow][skoff] = rv[it];
    }
    __syncthreads();

    // S^T tiles: bias^T as accumulator init, loaded at use
    floatx16 s0, s1;
#pragma unroll
    for (int rr = 0; rr < 4; ++rr) {
      float4 b0 = bp[rr * 64];
      float4 b1 = bp[(4 + rr) * 64];
      s0[rr * 4 + 0] = b0.x; s0[rr * 4 + 1] = b0.y; s0[rr * 4 + 2] = b0.z; s0[rr * 4 + 3] = b0.w;
      s1[rr * 4 + 0] = b1.x; s1[rr * 4 + 1] = b1.y; s1[rr * 4 + 2] = b1.z; s1[rr * 4 + 3] = b1.w;
    }
    bp += 512;

    if (c < 15) {                  // register prefetch of chunk c+1 K/V
      kp += (size_t)64 * H_ * DH_;
      vp += 64;
#pragma unroll
      for (int it = 0; it < 2; ++it) {
        rk[it] = *(const short8*)(kp + (size_t)it * 32 * H_ * DH_);
        rv[it] = *(const short8*)(vp + (size_t)it * 32 * L_);
      }
    }

#pragma unroll
    for (int ks = 0; ks < 4; ++ks) {
      half8 bk0 = *(const half8*)&lK[c32][ks * 16 + hi * 8];
      half8 bk1 = *(const half8*)&lK[32 + c32][ks * 16 + hi * 8];
      s0 = __builtin_amdgcn_mfma_f32_32x32x16_f16(bk0, aq[ks], s0, 0, 0, 0);
      s1 = __builtin_amdgcn_mfma_f32_32x32x16_f16(bk1, aq[ks], s1, 0, 0, 0);
    }

    // softmax weights (exp2; shift folded into bias) -> in-register bf16 PV A-frags
    union { short8 v[4]; unsigned u[16]; } ap;
#pragma unroll
    for (int reg = 0; reg < 16; ++reg) {
      float p0 = EXP2(s0[reg]);
      float p1 = EXP2(s1[reg]);
      ap.u[reg] = pack_bf2(p0, p1);
      if (reg & 1) rsum1 += p0 + p1; else rsum0 += p0 + p1;
    }

    // O += P V (2 dh-tiles), bf16
#pragma unroll
    for (int ks = 0; ks < 4; ++ks) {
      short8 bv0 = *(const short8*)&lVt[c32][ks * 16 + hi * 8];
      short8 bv1 = *(const short8*)&lVt[32 + c32][ks * 16 + hi * 8];
      acc0 = __builtin_amdgcn_mfma_f32_32x32x16_bf16(ap.v[ks], bv0, acc0, 0, 0, 0);
      acc1 = __builtin_amdgcn_mfma_f32_32x32x16_bf16(ap.v[ks], bv1, acc1, 0, 0, 0);
    }
  }

  // rowsum: combine hi halves, broadcast via wave-private LDS.
  float rsum = rsum0 + rsum1;
  rsum += __shfl_xor(rsum, 32, 64);
  if (hi == 0) lRS[w][c32] = rsum;

  // epilogue: normalize (acc C-layout: row=(reg&3)+8*(reg>>2)+4*hi, col=dh=c32)
#pragma unroll
  for (int reg = 0; reg < 16; ++reg) {
    int rl = (reg & 3) + 8 * (reg >> 2) + 4 * hi;
    float inv = 1.0f / lRS[w][rl];
    int row = qr0 + rl;
    size_t obase = ((size_t)((b * L_ + row) * H_ + h)) * DH_;
    o[obase + c32]      = f2h(acc0[reg] * inv);
    o[obase + 32 + c32] = f2h(acc1[reg] * inv);
  }
}

// ---------------------------------------------------------------- launch
extern "C" void kernel_launch(void* const* d_in, const int* in_sizes, int n_in,
                              void* d_out, int out_size, void* d_ws, size_t ws_size,
                              hipStream_t stream) {
  const float* x    = (const float*)d_in[0];
  const float* mask = (const float*)d_in[1];
  const float* Wk   = (const float*)d_in[2];
  const float* Wv   = (const float*)d_in[3];
  const float* Wq   = (const float*)d_in[4];
  const float* Wo   = (const float*)d_in[5];

  char* ws = (char*)d_ws;
  u16* xf    = (u16*)(ws);                        // 16 MB x f16 ; later attn out f16
  u16* aout  = xf;
  u16* kf    = (u16*)(ws + (16ull << 20));        // 16 MB k f16
  u16* vtb   = (u16*)(ws + (32ull << 20));        // 16 MB transposed+permuted V bf16
  float* biasP = (float*)(ws + (48ull << 20));    // 4 MB permuted bias^T (log2e-scaled)
  u16* wqf   = (u16*)(ws + (52ull << 20));        // 2 MB each, f16 weights
  u16* wkf   = (u16*)(ws + (54ull << 20));
  u16* wvf   = (u16*)(ws + (56ull << 20));
  u16* wof   = (u16*)(ws + (58ull << 20));
  // d_out (32 MB): qf (lower 16) -> final fp32 out overwrites
  u16* qf = (u16*)d_out;

  cast_all<<<16384, 256, 0, stream>>>(x, Wq, Wk, Wv, Wo, mask,
                                      xf, wqf, wkf, wvf, wof, biasP);

  gemm_qkv<<<dim3(24, 64), 256, 0, stream>>>(xf, wqf, wkf, wvf, qf, kf, vtb);

  attn_kernel<<<dim3(B_ * H_, L_ / 128), 256, 0, stream>>>(qf, kf, vtb, biasP, aout);

  gemm_fin<<<dim3(D_ / 128, (B_ * L_) / 128), 256, 0, stream>>>(
      aout, wof, (float*)d_out, B_ * L_, D_, D_);
}

// Round 14
// 246.348 us; speedup vs baseline: 1.0583x; 1.0005x over previous
//
#include <hip/hip_runtime.h>

// Problem constants (B=8, L=1024, D=1024, H=16, DH=64)
#define B_  8
#define L_  1024
#define D_  1024
#define H_  16
#define DH_ 64

typedef unsigned short u16;
typedef __attribute__((ext_vector_type(8))) short short8;      // 8 x u16 bag (bf16)
typedef __attribute__((ext_vector_type(8))) _Float16 half8;    // 8 x f16
typedef __attribute__((ext_vector_type(4))) float floatx4;     // 16x16 C/D frag
typedef __attribute__((ext_vector_type(16))) float floatx16;   // 32x32 C/D frag

// fp32 -> bf16 round-to-nearest-even
static __device__ __forceinline__ u16 f2bf(float f) {
  union { float f; unsigned u; } cv; cv.f = f;
  unsigned u = cv.u;
  return (u16)((u + 0x7fffu + ((u >> 16) & 1u)) >> 16);
}
// fp32 -> f16 (RNE)
static __device__ __forceinline__ u16 f2h(float f) {
  union { _Float16 h; u16 u; } cv; cv.h = (_Float16)f; return cv.u;
}
// pack two fp32 -> two bf16 via v_perm; low u16 = a, high u16 = b
static __device__ __forceinline__ unsigned pack_bf2(float a, float b) {
  union { float f; unsigned u; } ua, ub; ua.f = a; ub.f = b;
  return __builtin_amdgcn_perm(ub.u + 0x8000u, ua.u + 0x8000u, 0x07060302u);
}

#if __has_builtin(__builtin_amdgcn_exp2f)
#define EXP2(x) __builtin_amdgcn_exp2f(x)
#else
#define EXP2(x) __expf((x) * 0.6931471805599453f)
#endif

// ---------------------------------------------------------------- fused casts + bias permute
// blocks [0,12288): cast x/Wq/Wk/Wv/Wo fp32 -> f16
// blocks [12288,16384): permuted bias^T table, PRE-MULTIPLIED by log2(e)
__global__ void cast_all(const float* __restrict__ x,  const float* __restrict__ wq,
                         const float* __restrict__ wk, const float* __restrict__ wv,
                         const float* __restrict__ wo, const float* __restrict__ mask,
                         u16* __restrict__ xf,  u16* __restrict__ wqf,
                         u16* __restrict__ wkf, u16* __restrict__ wvf,
                         u16* __restrict__ wof, float* __restrict__ biasP) {
  int blk = blockIdx.x;
  if (blk >= 12288) {
    int i = (blk - 12288) * 256 + threadIdx.x;
    int e = i & 3, lane = (i >> 2) & 63, rr = (i >> 8) & 3, t = (i >> 10) & 1;
    int c = (i >> 11) & 15, w = (i >> 15) & 3, qt = i >> 17;
    int kk  = e + 8 * rr + 4 * (lane >> 5);
    int row = qt * 128 + w * 32 + (lane & 31);
    int key = c * 64 + t * 32 + kk;
    // log2e * ((mask-1)*1.25e8 - 24)
    biasP[i] = (mask[(size_t)row * L_ + key] - 1.0f) * 1.8033688e8f - 34.624681f;
    return;
  }
  const float* src; u16* dst; int off;
  if (blk < 8192)       { src = x;  dst = xf;  off = blk; }
  else if (blk < 9216)  { src = wq; dst = wqf; off = blk - 8192; }
  else if (blk < 10240) { src = wk; dst = wkf; off = blk - 9216; }
  else if (blk < 11264) { src = wv; dst = wvf; off = blk - 10240; }
  else                  { src = wo; dst = wof; off = blk - 11264; }
  int i = off * 1024 + threadIdx.x * 4;
  float4 f = *(const float4*)(src + i);
  ushort4 r;
  r.x = f2h(f.x); r.y = f2h(f.y); r.z = f2h(f.z); r.w = f2h(f.w);
  *(ushort4*)(dst + i) = r;
}

// ---------------------------------------------------------------- LDS staging helper
typedef __attribute__((address_space(3))) void  lds_void;
typedef const __attribute__((address_space(1))) void g_void;
static __device__ __forceinline__ void load_lds16(const void* g, void* l) {
  __builtin_amdgcn_global_load_lds((g_void*)g, (lds_void*)l, 16, 0, 0);
}

// ---------------------------------------------------------------- fused QKV GEMM (BT), f16 inputs
// grid (24, 64): n-blocks 0-7 -> q (scale 1/8*log2e, f16), 8-15 -> k (f16),
// 16-23 -> v (bf16, transposed+key-permuted vt layout via an LDS roundtrip,
// row stride 130 u16 -> column-gather reads 2-way/free; r11 PMC:
// conflicts 1.05M -> 262K, 73.1 us -> r12 72.0 us).
// K-loop: LDS double-buffered BK=32 tiles, counted vmcnt(4), chunk-XOR swizzle.
__global__ __launch_bounds__(256) void gemm_qkv(const u16* __restrict__ A,
                                                const u16* __restrict__ wq,
                                                const u16* __restrict__ wk,
                                                const u16* __restrict__ wv,
                                                u16* __restrict__ qf,
                                                u16* __restrict__ kf,
                                                u16* __restrict__ vt) {
  const int K = D_, N = D_;
  int nb = blockIdx.x;
  const u16* Bw; u16* Cp; float scale; int obf;
  if (nb < 8)       { Bw = wq; Cp = qf; scale = 0.18033688f; obf = 0; }  // 0.125*log2e
  else if (nb < 16) { Bw = wk; Cp = kf; scale = 1.0f;        obf = 0; }
  else              { Bw = wv; Cp = vt; scale = 1.0f;        obf = 1; }
  const int n0 = (nb & 7) * 128;

  // pool: first 16384 = staging (lA 8192 | lB 8192); as 128x130 transpose tile
  // for the V epilogue it needs 128*130 = 16640.
  __shared__ u16 pool[16640];
  u16* lA = pool;
  u16* lB = pool + 8192;
  const int tid  = threadIdx.x;
  const int w    = tid >> 6;
  const int lane = tid & 63;
  const int m    = lane & 15;
  const int kg   = lane >> 4;
  const int m0   = blockIdx.y * 128;
  const int wm   = (w >> 1) * 64;
  const int wn   = (w & 1) * 64;
  const int rowS = tid >> 2;
  const int part = tid & 3;
  // swizzle: stored chunk c' holds global chunk c' ^ ((row>>1)&3)
  const int csrc8 = ((part ^ ((rowS >> 1) & 3))) * 8;   // staging source column
  const int kgs   = (kg ^ ((m >> 1) & 3)) * 8;          // fragment read column

  floatx4 acc[4][4];
#pragma unroll
  for (int i = 0; i < 4; ++i)
#pragma unroll
    for (int j = 0; j < 4; ++j)
#pragma unroll
      for (int r = 0; r < 4; ++r) acc[i][j][r] = 0.0f;

  auto STAGE = [&](int k0, int bufsel) {
#pragma unroll
    for (int rnd = 0; rnd < 2; ++rnd) {
      const u16* ga = A  + (size_t)(m0 + rnd * 64 + rowS) * K + k0 + csrc8;
      const u16* gb = Bw + (size_t)(n0 + rnd * 64 + rowS) * K + k0 + csrc8;
      load_lds16(ga, lA + bufsel * 4096 + rnd * 2048 + w * 512);
      load_lds16(gb, lB + bufsel * 4096 + rnd * 2048 + w * 512);
    }
  };

  STAGE(0, 0);
  STAGE(32, 1);

  for (int k0 = 0; k0 < K; k0 += 32) {
    const int buf = (k0 >> 5) & 1;
    if (k0 + 32 < K) { asm volatile("s_waitcnt vmcnt(4)" ::: "memory"); }
    else             { asm volatile("s_waitcnt vmcnt(0)" ::: "memory"); }
    __builtin_amdgcn_s_barrier();
    __builtin_amdgcn_sched_barrier(0);

    const u16* pA = lA + buf * 4096;
    const u16* pB = lB + buf * 4096;
    half8 af[4], bf[4];
#pragma unroll
    for (int i = 0; i < 4; ++i) af[i] = *(const half8*)&pA[(wm + i * 16 + m) * 32 + kgs];
#pragma unroll
    for (int i = 0; i < 4; ++i) bf[i] = *(const half8*)&pB[(wn + i * 16 + m) * 32 + kgs];
#pragma unroll
    for (int mi = 0; mi < 4; ++mi)
#pragma unroll
      for (int ni = 0; ni < 4; ++ni)
        acc[mi][ni] = __builtin_amdgcn_mfma_f32_16x16x32_f16(af[mi], bf[ni], acc[mi][ni], 0, 0, 0);

    __builtin_amdgcn_sched_barrier(0);
    __builtin_amdgcn_s_barrier();
    if (k0 + 64 < K) STAGE(k0 + 64, buf);
  }

  if (!obf) {
    // q/k: normal f16 store
#pragma unroll
    for (int mi = 0; mi < 4; ++mi)
#pragma unroll
      for (int ni = 0; ni < 4; ++ni)
#pragma unroll
        for (int r = 0; r < 4; ++r) {
          int row = m0 + wm + mi * 16 + kg * 4 + r;
          int col = n0 + wn + ni * 16 + m;
          Cp[(size_t)row * N + col] = f2h(acc[mi][ni][r] * scale);
        }
  } else {
    // V: bf16 tile -> LDS (128 rows x stride 130) -> transposed+permuted store.
#pragma unroll
    for (int mi = 0; mi < 4; ++mi)
#pragma unroll
      for (int ni = 0; ni < 4; ++ni)
#pragma unroll
        for (int r = 0; r < 4; ++r) {
          int rl = wm + mi * 16 + kg * 4 + r;      // 0..127 local row (l - m0)
          int cl = wn + ni * 16 + m;               // 0..127 local col (e - n0)
          pool[rl * 130 + cl] = f2bf(acc[mi][ni][r]);
        }
    __syncthreads();
    const int b  = m0 >> 10;                       // batch of this 128-row strip
    const int l0 = m0 & 1023;                      // row offset within sequence
    const int h0 = (nb & 7) * 2;                   // first head of this col strip
    const int j  = tid >> 2;                       // dh (0..63)
    const int p0 = (tid & 3) * 16;                 // position base
#pragma unroll
    for (int hh = 0; hh < 2; ++hh) {
#pragma unroll
      for (int cc = 0; cc < 2; ++cc) {
        __attribute__((aligned(16))) u16 tmp[16];
#pragma unroll
        for (int s = 0; s < 16; ++s) {
          int p   = p0 + s;
          int l64 = (p >> 1) + ((p & 1) << 5);     // key within 64-chunk at pos p
          tmp[s] = pool[(cc * 64 + l64) * 130 + hh * 64 + j];
        }
        u16* dst = vt + ((size_t)((b * H_ + h0 + hh) * DH_ + j)) * L_ + l0 + cc * 64 + p0;
        *(short8*)(dst)     = *(const short8*)&tmp[0];
        *(short8*)(dst + 8) = *(const short8*)&tmp[8];
      }
    }
  }
}

// ---------------------------------------------------------------- final GEMM (BT), f16 in, fp32 out
// grid (8, 64), XCD-grouped remap: each XCD owns 8 consecutive row-panels
// (all 8 col-blocks of a panel on one XCD -> A-panel 2 MB + Wo 2 MB = one L2).
__global__ __launch_bounds__(256) void gemm_fin(const u16* __restrict__ A,
                                                const u16* __restrict__ Bw,
                                                float* __restrict__ Cp,
                                                int M, int N, int K) {
  __shared__ u16 lA[2 * 128 * 32];
  __shared__ u16 lB[2 * 128 * 32];
  const int tid  = threadIdx.x;
  const int w    = tid >> 6;
  const int lane = tid & 63;
  const int m    = lane & 15;
  const int kg   = lane >> 4;
  // bijective XCD-grouping remap (assumes round-robin flat->XCD dispatch):
  // xcd = flat&7 handles row-panels yb in [xcd*8, xcd*8+8), all 8 col-blocks.
  const int flat = blockIdx.y * 8 + blockIdx.x;
  const int idx  = flat >> 3;
  const int yb   = ((flat & 7) << 3) | (idx & 7);
  const int xb   = idx >> 3;
  const int m0   = yb * 128;
  const int n0   = xb * 128;
  const int wm   = (w >> 1) * 64;
  const int wn   = (w & 1) * 64;
  const int rowS = tid >> 2;
  const int part = tid & 3;
  const int csrc8 = ((part ^ ((rowS >> 1) & 3))) * 8;
  const int kgs   = (kg ^ ((m >> 1) & 3)) * 8;

  floatx4 acc[4][4];
#pragma unroll
  for (int i = 0; i < 4; ++i)
#pragma unroll
    for (int j = 0; j < 4; ++j)
#pragma unroll
      for (int r = 0; r < 4; ++r) acc[i][j][r] = 0.0f;

  auto STAGE = [&](int k0, int bufsel) {
#pragma unroll
    for (int rnd = 0; rnd < 2; ++rnd) {
      const u16* ga = A  + (size_t)(m0 + rnd * 64 + rowS) * K + k0 + csrc8;
      const u16* gb = Bw + (size_t)(n0 + rnd * 64 + rowS) * K + k0 + csrc8;
      load_lds16(ga, lA + bufsel * 4096 + rnd * 2048 + w * 512);
      load_lds16(gb, lB + bufsel * 4096 + rnd * 2048 + w * 512);
    }
  };

  STAGE(0, 0);
  STAGE(32, 1);

  for (int k0 = 0; k0 < K; k0 += 32) {
    const int buf = (k0 >> 5) & 1;
    if (k0 + 32 < K) { asm volatile("s_waitcnt vmcnt(4)" ::: "memory"); }
    else             { asm volatile("s_waitcnt vmcnt(0)" ::: "memory"); }
    __builtin_amdgcn_s_barrier();
    __builtin_amdgcn_sched_barrier(0);

    const u16* pA = lA + buf * 4096;
    const u16* pB = lB + buf * 4096;
    half8 af[4], bf[4];
#pragma unroll
    for (int i = 0; i < 4; ++i) af[i] = *(const half8*)&pA[(wm + i * 16 + m) * 32 + kgs];
#pragma unroll
    for (int i = 0; i < 4; ++i) bf[i] = *(const half8*)&pB[(wn + i * 16 + m) * 32 + kgs];
#pragma unroll
    for (int mi = 0; mi < 4; ++mi)
#pragma unroll
      for (int ni = 0; ni < 4; ++ni)
        acc[mi][ni] = __builtin_amdgcn_mfma_f32_16x16x32_f16(af[mi], bf[ni], acc[mi][ni], 0, 0, 0);

    __builtin_amdgcn_sched_barrier(0);
    __builtin_amdgcn_s_barrier();
    if (k0 + 64 < K) STAGE(k0 + 64, buf);
  }

#pragma unroll
  for (int mi = 0; mi < 4; ++mi)
#pragma unroll
    for (int ni = 0; ni < 4; ++ni)
#pragma unroll
      for (int r = 0; r < 4; ++r) {
        int row = m0 + wm + mi * 16 + kg * 4 + r;
        int col = n0 + wn + ni * 16 + m;
        Cp[(size_t)row * N + col] = acc[mi][ni][r];
      }
}

// ---------------------------------------------------------------- fused flash attention, 32x32 MFMA
// grid (128, 8) flat-remapped: each XCD owns 16 consecutive bh (K/V 4 MB = L2).
// Round-4 register-diet body (<=128 regs, 4 waves/SIMD). Float bias^T C-init.
__global__ __launch_bounds__(256, 4) void attn_kernel(const u16* __restrict__ q,
                                                      const u16* __restrict__ k,
                                                      const u16* __restrict__ vt,
                                                      const float* __restrict__ biasP,
                                                      u16* __restrict__ o) {
  __shared__ u16 lK[64][72];       // f16, [key][dh]
  __shared__ u16 lVt[64][72];      // bf16, [dh][pos] (permuted keys)
  __shared__ float lRS[4][32];     // per-wave rowsum broadcast

  // XCD-grouping remap (bijective): xcd = flat&7 owns bh in [xcd*16, xcd*16+16).
  const int flat = blockIdx.y * 128 + blockIdx.x;
  const int idx  = flat >> 3;
  const int bh   = ((flat & 7) << 4) | (idx & 15);
  const int qt   = idx >> 4;

  const int b = bh >> 4, h = bh & 15;
  const int tid = threadIdx.x;
  const int w = tid >> 6, lane = tid & 63;
  const int c32 = lane & 31, hi = lane >> 5;
  const int qr0 = qt * 128 + w * 32;

  const int srow  = tid >> 3;      // 0..31 (stages 2 rows via it)
  const int skoff = (tid & 7) * 8;

  // Q B-frags: lane holds Q[q=qr0+c32][dh-slice ks*16+hi*8]
  const size_t qbase = ((size_t)((b * L_ + qr0 + c32) * H_ + h)) * DH_;
  half8 aq[4];
#pragma unroll
  for (int ks = 0; ks < 4; ++ks)
    aq[ks] = *(const half8*)(q + qbase + ks * 16 + hi * 8);

  floatx16 acc0, acc1;
#pragma unroll
  for (int i = 0; i < 16; ++i) { acc0[i] = 0.0f; acc1[i] = 0.0f; }
  float rsum0 = 0.0f, rsum1 = 0.0f;

  // staging pointers (chunk 0), advanced by constant stride per chunk
  const u16* kp = k  + ((size_t)((b * L_ + srow) * H_ + h)) * DH_ + skoff;
  const u16* vp = vt + ((size_t)((b * H_ + h) * DH_ + srow)) * L_ + skoff;

  short8 rk[2], rv[2];             // chunk-0 K/V prefetch
#pragma unroll
  for (int it = 0; it < 2; ++it) {
    rk[it] = *(const short8*)(kp + (size_t)it * 32 * H_ * DH_);
    rv[it] = *(const short8*)(vp + (size_t)it * 32 * L_);
  }

  const float4* bp = (const float4*)(biasP + ((size_t)(qt * 4 + w) * 16) * 2048) + lane;

  for (int c = 0; c < 16; ++c) {
    __syncthreads();               // previous chunk readers done
#pragma unroll
    for (int it = 0; it < 2; ++it) {
      *(short8*)&lK[it * 32 + srow][skoff]  = rk[it];
      *(short8*)&lVt[it * 32 + srow][skoff] = rv[it];
    }
    __syncthreads();

    // S^T tiles: bias^T as accumulator init, loaded at use
    floatx16 s0, s1;
#pragma unroll
    for (int rr = 0; rr < 4; ++rr) {
      float4 b0 = bp[rr * 64];
      float4 b1 = bp[(4 + rr) * 64];
      s0[rr * 4 + 0] = b0.x; s0[rr * 4 + 1] = b0.y; s0[rr * 4 + 2] = b0.z; s0[rr * 4 + 3] = b0.w;
      s1[rr * 4 + 0] = b1.x; s1[rr * 4 + 1] = b1.y; s1[rr * 4 + 2] = b1.z; s1[rr * 4 + 3] = b1.w;
    }
    bp += 512;

    if (c < 15) {                  // register prefetch of chunk c+1 K/V
      kp += (size_t)64 * H_ * DH_;
      vp += 64;
#pragma unroll
      for (int it = 0; it < 2; ++it) {
        rk[it] = *(const short8*)(kp + (size_t)it * 32 * H_ * DH_);
        rv[it] = *(const short8*)(vp + (size_t)it * 32 * L_);
      }
    }

#pragma unroll
    for (int ks = 0; ks < 4; ++ks) {
      half8 bk0 = *(const half8*)&lK[c32][ks * 16 + hi * 8];
      half8 bk1 = *(const half8*)&lK[32 + c32][ks * 16 + hi * 8];
      s0 = __builtin_amdgcn_mfma_f32_32x32x16_f16(bk0, aq[ks], s0, 0, 0, 0);
      s1 = __builtin_amdgcn_mfma_f32_32x32x16_f16(bk1, aq[ks], s1, 0, 0, 0);
    }

    // softmax weights (exp2; shift folded into bias) -> in-register bf16 PV A-frags
    union { short8 v[4]; unsigned u[16]; } ap;
#pragma unroll
    for (int reg = 0; reg < 16; ++reg) {
      float p0 = EXP2(s0[reg]);
      float p1 = EXP2(s1[reg]);
      ap.u[reg] = pack_bf2(p0, p1);
      if (reg & 1) rsum1 += p0 + p1; else rsum0 += p0 + p1;
    }

    // O += P V (2 dh-tiles), bf16
#pragma unroll
    for (int ks = 0; ks < 4; ++ks) {
      short8 bv0 = *(const short8*)&lVt[c32][ks * 16 + hi * 8];
      short8 bv1 = *(const short8*)&lVt[32 + c32][ks * 16 + hi * 8];
      acc0 = __builtin_amdgcn_mfma_f32_32x32x16_bf16(ap.v[ks], bv0, acc0, 0, 0, 0);
      acc1 = __builtin_amdgcn_mfma_f32_32x32x16_bf16(ap.v[ks], bv1, acc1, 0, 0, 0);
    }
  }

  // rowsum: combine hi halves, broadcast via wave-private LDS.
  float rsum = rsum0 + rsum1;
  rsum += __shfl_xor(rsum, 32, 64);
  if (hi == 0) lRS[w][c32] = rsum;

  // epilogue: normalize (acc C-layout: row=(reg&3)+8*(reg>>2)+4*hi, col=dh=c32)
#pragma unroll
  for (int reg = 0; reg < 16; ++reg) {
    int rl = (reg & 3) + 8 * (reg >> 2) + 4 * hi;
    float inv = 1.0f / lRS[w][rl];
    int row = qr0 + rl;
    size_t obase = ((size_t)((b * L_ + row) * H_ + h)) * DH_;
    o[obase + c32]      = f2h(acc0[reg] * inv);
    o[obase + 32 + c32] = f2h(acc1[reg] * inv);
  }
}

// ---------------------------------------------------------------- launch
extern "C" void kernel_launch(void* const* d_in, const int* in_sizes, int n_in,
                              void* d_out, int out_size, void* d_ws, size_t ws_size,
                              hipStream_t stream) {
  const float* x    = (const float*)d_in[0];
  const float* mask = (const float*)d_in[1];
  const float* Wk   = (const float*)d_in[2];
  const float* Wv   = (const float*)d_in[3];
  const float* Wq   = (const float*)d_in[4];
  const float* Wo   = (const float*)d_in[5];

  char* ws = (char*)d_ws;
  u16* xf    = (u16*)(ws);                        // 16 MB x f16 ; later attn out f16
  u16* aout  = xf;
  u16* kf    = (u16*)(ws + (16ull << 20));        // 16 MB k f16
  u16* vtb   = (u16*)(ws + (32ull << 20));        // 16 MB transposed+permuted V bf16
  float* biasP = (float*)(ws + (48ull << 20));    // 4 MB permuted bias^T (log2e-scaled)
  u16* wqf   = (u16*)(ws + (52ull << 20));        // 2 MB each, f16 weights
  u16* wkf   = (u16*)(ws + (54ull << 20));
  u16* wvf   = (u16*)(ws + (56ull << 20));
  u16* wof   = (u16*)(ws + (58ull << 20));
  // d_out (32 MB): qf (lower 16) -> final fp32 out overwrites
  u16* qf = (u16*)d_out;

  cast_all<<<16384, 256, 0, stream>>>(x, Wq, Wk, Wv, Wo, mask,
                                      xf, wqf, wkf, wvf, wof, biasP);

  gemm_qkv<<<dim3(24, 64), 256, 0, stream>>>(xf, wqf, wkf, wvf, qf, kf, vtb);

  attn_kernel<<<dim3(B_ * H_, L_ / 128), 256, 0, stream>>>(qf, kf, vtb, biasP, aout);

  gemm_fin<<<dim3(D_ / 128, (B_ * L_) / 128), 256, 0, stream>>>(
      aout, wof, (float*)d_out, B_ * L_, D_, D_);
}